// Round 5
// baseline (503.767 us; speedup 1.0000x reference)
//
#include <hip/hip_runtime.h>
#include <cstddef>

#define BATCH   4096
#define PAD_IDX 1000000
#define NEG_INF_F (-1e9f)
#define EMB_FLOATS 64000064   // (1e6+1) * 64

typedef __attribute__((ext_vector_type(8))) short bf16x8;   // 8 bf16 = 4 VGPRs
typedef __attribute__((ext_vector_type(4))) float f32x4;
typedef unsigned short u16;

__device__ __forceinline__ u16 f2bf(float f) {              // RNE fp32 -> bf16
    unsigned u = __float_as_uint(f);
    return (u16)((u + 0x7fffu + ((u >> 16) & 1u)) >> 16);
}

// Online-softmax update on named state (mm, dd, aa)
#define UPD(mm, dd, aa, s, v)                          \
    {                                                  \
        float nm = fmaxf(mm, (s));                     \
        float sc = __expf(mm - nm);                    \
        float e  = __expf((s) - nm);                   \
        dd = fmaf(dd, sc, e);                          \
        aa.x = fmaf(aa.x, sc, e * (v).x);              \
        aa.y = fmaf(aa.y, sc, e * (v).y);              \
        aa.z = fmaf(aa.z, sc, e * (v).z);              \
        aa.w = fmaf(aa.w, sc, e * (v).w);              \
        mm = nm;                                       \
    }

// Flash-merge state (m,d,acc) with partner at lane^P
#define MERGE(P)                                                  \
    {                                                             \
        float mo  = __shfl_xor(m, P);                             \
        float d_o = __shfl_xor(d, P);                             \
        float ax = __shfl_xor(acc.x, P);                          \
        float ay = __shfl_xor(acc.y, P);                          \
        float az = __shfl_xor(acc.z, P);                          \
        float aw = __shfl_xor(acc.w, P);                          \
        float nm = fmaxf(m, mo);                                  \
        float sA = __expf(m - nm), sB = __expf(mo - nm);          \
        d = d * sA + d_o * sB;                                    \
        acc.x = acc.x * sA + ax * sB;                             \
        acc.y = acc.y * sA + ay * sB;                             \
        acc.z = acc.z * sA + az * sB;                             \
        acc.w = acc.w * sA + aw * sB;                             \
        m = nm;                                                   \
    }

#define QRED(s)                       \
    s += __shfl_xor(s, 1);            \
    s += __shfl_xor(s, 2);            \
    s += __shfl_xor(s, 4);            \
    s += __shfl_xor(s, 8);

#define DOT4(v, a) ((v).x * (a).x + (v).y * (a).y + (v).z * (a).z + (v).w * (a).w)

// ---------------- prep: L3 table warm + attention pools + ad gather + weight transpose ----------------
// Blocks [0, 2048):          warm — stream 128 KB each of emb into L3 (poison/restore left it cold).
// Blocks [2048, 2048+5120):  build_x — 4 waves/block, wave split into 4x16-lane quarters.
// Blocks [7168, 7680):       32x32 LDS-tiled transpose W[K][N] fp32 -> WT[N][K] bf16.
// x row layout (704 bf16): [pool_item(64) | pool_author(64) | pool_music(64) | ad(512)]
__global__ void __launch_bounds__(256) prep_kernel(
    const int* __restrict__ fidx,
    const int* __restrict__ hist_item,
    const int* __restrict__ hist_author,
    const int* __restrict__ hist_music,
    const float* __restrict__ emb,
    const float* __restrict__ W1, const float* __restrict__ W2, const float* __restrict__ W3,
    u16* __restrict__ x,
    u16* __restrict__ w1t, u16* __restrict__ w2t, u16* __restrict__ w3t)
{
    __shared__ float tile[32][33];
    const int blk = blockIdx.x;
    const int tid = threadIdx.x;

    if (blk < 2048) {
        // ---- warm: 2048 blocks x 128 KB = 256 MB streaming read of the table ----
        float s = 0.f;
        const size_t base = (size_t)blk * 32768 + tid * 4;
#pragma unroll 8
        for (int i = 0; i < 32; ++i) {
            const size_t fi = base + (size_t)i * 1024;
            if (fi + 4 <= EMB_FLOATS) {
                const float4 v = *(const float4*)(emb + fi);
                s += v.x + v.y + v.z + v.w;
            }
        }
        // impossible (|s| < 1e6), but the compiler can't prove it -> loads not elided
        if (s == 1.2345e37f) x[0] = 1;
        return;
    }

    if (blk < 7168) {
        const int w    = (blk - 2048) * 4 + (tid >> 6);
        const int lane = tid & 63;
        const int t16  = lane & 15;
        const int q    = lane >> 4;

        if (w < 3 * BATCH) {
            const int h = w >> 12;
            const int b = w & (BATCH - 1);
            int L, col, off;
            const int* hrow;
            if (h == 0)      { L = 350; col = 2; off = 0;   hrow = hist_item   + (size_t)b * 350; }
            else if (h == 1) { L = 250; col = 3; off = 64;  hrow = hist_author + (size_t)b * 250; }
            else             { L = 100; col = 6; off = 128; hrow = hist_music  + (size_t)b * 100; }

            const int ad_idx = fidx[b * 8 + col];
            const float4 ad4 = *(const float4*)(emb + (size_t)ad_idx * 64 + 4 * t16);

            float m = NEG_INF_F, d = 0.f;
            float4 acc = make_float4(0.f, 0.f, 0.f, 0.f);
            float mB = NEG_INF_F, dB = 0.f;
            float4 aB = make_float4(0.f, 0.f, 0.f, 0.f);

            int l = 0;
            if (L >= 16) {
                int n0 = hrow[q], n1 = hrow[4 + q], n2 = hrow[8 + q], n3 = hrow[12 + q];
                while (true) {
                    const int i0 = n0, i1 = n1, i2 = n2, i3 = n3;
                    const float4 v0 = *(const float4*)(emb + (size_t)i0 * 64 + 4 * t16);
                    const float4 v1 = *(const float4*)(emb + (size_t)i1 * 64 + 4 * t16);
                    const float4 v2 = *(const float4*)(emb + (size_t)i2 * 64 + 4 * t16);
                    const float4 v3 = *(const float4*)(emb + (size_t)i3 * 64 + 4 * t16);
                    l += 16;
                    const bool more = (l + 16 <= L);
                    if (more) {
                        n0 = hrow[l + q];      n1 = hrow[l + 4 + q];
                        n2 = hrow[l + 8 + q];  n3 = hrow[l + 12 + q];
                    }
                    float s0 = DOT4(v0, ad4);
                    float s1 = DOT4(v1, ad4);
                    float s2 = DOT4(v2, ad4);
                    float s3 = DOT4(v3, ad4);
                    QRED(s0) QRED(s1) QRED(s2) QRED(s3)
                    if (i0 == PAD_IDX) s0 = NEG_INF_F;
                    if (i1 == PAD_IDX) s1 = NEG_INF_F;
                    if (i2 == PAD_IDX) s2 = NEG_INF_F;
                    if (i3 == PAD_IDX) s3 = NEG_INF_F;
                    UPD(m, d, acc, s0, v0)
                    UPD(mB, dB, aB, s1, v1)
                    UPD(m, d, acc, s2, v2)
                    UPD(mB, dB, aB, s3, v3)
                    if (!more) break;
                }
            }
            for (; l < L; l += 4) {
                const int li = l + q;
                const int i0 = (li < L) ? hrow[li] : PAD_IDX;
                const float4 v0 = *(const float4*)(emb + (size_t)i0 * 64 + 4 * t16);
                float s0 = DOT4(v0, ad4);
                QRED(s0)
                if (i0 == PAD_IDX) s0 = NEG_INF_F;
                UPD(m, d, acc, s0, v0)
            }

            {   // merge B into A (local)
                float nm = fmaxf(m, mB);
                float eA = __expf(m - nm), eB = __expf(mB - nm);
                d = d * eA + dB * eB;
                acc.x = acc.x * eA + aB.x * eB;
                acc.y = acc.y * eA + aB.y * eB;
                acc.z = acc.z * eA + aB.z * eB;
                acc.w = acc.w * eA + aB.w * eB;
                m = nm;
            }
            MERGE(16)
            MERGE(32)

            if (lane < 16) {
                const float inv = 1.f / d;
                uint2 p;
                p.x = (unsigned)f2bf(acc.x * inv) | ((unsigned)f2bf(acc.y * inv) << 16);
                p.y = (unsigned)f2bf(acc.z * inv) | ((unsigned)f2bf(acc.w * inv) << 16);
                *(uint2*)(x + (size_t)b * 704 + off + 4 * t16) = p;
            }
        } else {
            const int tt = w - 3 * BATCH;          // [0, 2B)
            const int b  = tt >> 1;
            const int f  = ((tt & 1) << 2) + q;
            const int idx = fidx[b * 8 + f];
            const float4 v = *(const float4*)(emb + (size_t)idx * 64 + 4 * t16);
            uint2 p;
            p.x = (unsigned)f2bf(v.x) | ((unsigned)f2bf(v.y) << 16);
            p.y = (unsigned)f2bf(v.z) | ((unsigned)f2bf(v.w) << 16);
            *(uint2*)(x + (size_t)b * 704 + 192 + (size_t)f * 64 + 4 * t16) = p;
        }
        return;
    }

    // ---- weight transpose: 32x32 fp32 tile, coalesced both ways ----
    int t = blk - 7168;
    const float* W; u16* WT; int K, N, tk, tn;
    if (t < 352)      { W = W1; WT = w1t; K = 704; N = 512; tk = t % 22; tn = t / 22; }
    else if (t < 480) { t -= 352; W = W2; WT = w2t; K = 512; N = 256; tk = t % 16; tn = t / 16; }
    else              { t -= 480; W = W3; WT = w3t; K = 256; N = 128; tk = t % 8;  tn = t / 8;  }
    const int k0 = tk * 32, n0 = tn * 32;
    const int tx = tid & 31, ty = tid >> 5;   // ty 0..7
#pragma unroll
    for (int j = 0; j < 4; ++j)
        tile[ty + 8 * j][tx] = W[(size_t)(k0 + ty + 8 * j) * N + n0 + tx];
    __syncthreads();
#pragma unroll
    for (int j = 0; j < 4; ++j)
        WT[(size_t)(n0 + ty + 8 * j) * K + k0 + tx] = f2bf(tile[tx][ty + 8 * j]);
}

// ---------------- layer 1: bf16 MFMA GEMM, C = relu(A @ BT^T + bias), bf16 out ----------------
// BM=64, BN=64, 256 threads = 4 waves, BK=32. LDS rows padded to 40 bf16.
// Fragments: A[m=lane&15][k=quad*8+j]; B[k=quad*8+j][n=lane&15]; C/D row=quad*4+reg, col=lane&15.
template <int BN>
__global__ void __launch_bounds__(256) gemm_mfma(
    const u16* __restrict__ A, const u16* __restrict__ BT,
    const float* __restrict__ bias, u16* __restrict__ C,
    int M, int N, int K)
{
    constexpr int NB = BN / 16;
    __shared__ u16 As[64][40];
    __shared__ u16 Bs[BN][40];

    const int tid  = threadIdx.x;
    const int wave = tid >> 6, lane = tid & 63;
    const int quad = lane >> 4, l16 = lane & 15;
    const int bm = blockIdx.y * 64, bn = blockIdx.x * BN;

    const int srow = tid >> 2;          // 0..63
    const int sk   = (tid & 3) * 8;     // 0,8,16,24

    f32x4 acc[NB];
#pragma unroll
    for (int i = 0; i < NB; ++i) acc[i] = (f32x4){0.f, 0.f, 0.f, 0.f};

    const size_t a_base = (size_t)(bm + srow) * K + sk;

    for (int k0 = 0; k0 < K; k0 += 32) {
        *(float4*)&As[srow][sk] = *(const float4*)(A + a_base + k0);
#pragma unroll
        for (int r0 = 0; r0 < BN; r0 += 64) {
            *(float4*)&Bs[r0 + srow][sk] =
                *(const float4*)(BT + (size_t)(bn + r0 + srow) * K + k0 + sk);
        }
        __syncthreads();

        const bf16x8 af = *(const bf16x8*)&As[wave * 16 + l16][quad * 8];
#pragma unroll
        for (int ni = 0; ni < NB; ++ni) {
            const bf16x8 bf = *(const bf16x8*)&Bs[ni * 16 + l16][quad * 8];
            acc[ni] = __builtin_amdgcn_mfma_f32_16x16x32_bf16(af, bf, acc[ni], 0, 0, 0);
        }
        __syncthreads();
    }

#pragma unroll
    for (int ni = 0; ni < NB; ++ni) {
        const int col = bn + ni * 16 + l16;
        const float bv = bias[col];
#pragma unroll
        for (int r = 0; r < 4; ++r) {
            const int row = bm + wave * 16 + quad * 4 + r;
            float v = fmaxf(acc[ni][r] + bv, 0.f);
            C[(size_t)row * N + col] = f2bf(v);
        }
    }
}

// ---------------- tail: out = relu(relu(h1@W2T^T+b2)@W3T^T+b3) @ Wo + bo ----------------
// 256 blocks x 16 rows. h2 kept in LDS (bf16, same rounding as before).
// Wave w: layer2 cols w*64..+64 (4 frags); layer3 cols w*32..+32 (2 frags); all 16 rows.
__global__ void __launch_bounds__(256) tail_mlp(
    const u16* __restrict__ h1, const u16* __restrict__ W2T, const u16* __restrict__ W3T,
    const float* __restrict__ b2, const float* __restrict__ b3,
    const float* __restrict__ Wo, const float* __restrict__ bo,
    float* __restrict__ out)
{
    __shared__ u16 As16[16][40];
    __shared__ u16 Bs[256][40];
    __shared__ u16 h2s[16][264];
    __shared__ float psum[16][4];

    const int tid  = threadIdx.x;
    const int wave = tid >> 6, lane = tid & 63;
    const int quad = lane >> 4, l16 = lane & 15;
    const int r0 = blockIdx.x * 16;

    // ---- layer 2: K=512, N=256 ----
    f32x4 acc2[4];
#pragma unroll
    for (int i = 0; i < 4; ++i) acc2[i] = (f32x4){0.f, 0.f, 0.f, 0.f};

    for (int k0 = 0; k0 < 512; k0 += 32) {
        if (tid < 64)
            *(float4*)&As16[tid >> 2][(tid & 3) * 8] =
                *(const float4*)(h1 + (size_t)(r0 + (tid >> 2)) * 512 + k0 + (tid & 3) * 8);
        {
            const u16* src = W2T + (size_t)tid * 512 + k0;
#pragma unroll
            for (int c = 0; c < 4; ++c)
                *(float4*)&Bs[tid][c * 8] = *(const float4*)(src + c * 8);
        }
        __syncthreads();

        const bf16x8 af = *(const bf16x8*)&As16[l16][quad * 8];
#pragma unroll
        for (int ni = 0; ni < 4; ++ni) {
            const bf16x8 bf = *(const bf16x8*)&Bs[wave * 64 + ni * 16 + l16][quad * 8];
            acc2[ni] = __builtin_amdgcn_mfma_f32_16x16x32_bf16(af, bf, acc2[ni], 0, 0, 0);
        }
        __syncthreads();
    }

    // bias + relu + bf16 round into LDS h2
#pragma unroll
    for (int ni = 0; ni < 4; ++ni) {
        const int col = wave * 64 + ni * 16 + l16;
        const float bv = b2[col];
#pragma unroll
        for (int r = 0; r < 4; ++r)
            h2s[quad * 4 + r][col] = f2bf(fmaxf(acc2[ni][r] + bv, 0.f));
    }
    __syncthreads();

    // ---- layer 3: K=256, N=128 ----
    f32x4 acc3[2];
#pragma unroll
    for (int i = 0; i < 2; ++i) acc3[i] = (f32x4){0.f, 0.f, 0.f, 0.f};

    for (int k0 = 0; k0 < 256; k0 += 32) {
        if (tid < 128) {
            const u16* src = W3T + (size_t)tid * 256 + k0;
#pragma unroll
            for (int c = 0; c < 4; ++c)
                *(float4*)&Bs[tid][c * 8] = *(const float4*)(src + c * 8);
        }
        __syncthreads();

        const bf16x8 af = *(const bf16x8*)&h2s[l16][k0 + quad * 8];
#pragma unroll
        for (int ni = 0; ni < 2; ++ni) {
            const bf16x8 bf = *(const bf16x8*)&Bs[wave * 32 + ni * 16 + l16][quad * 8];
            acc3[ni] = __builtin_amdgcn_mfma_f32_16x16x32_bf16(af, bf, acc3[ni], 0, 0, 0);
        }
        __syncthreads();
    }

    // epilogue: relu(+b3), dot with Wo over this wave's 32 cols, reduce over l16
    float part[4] = {0.f, 0.f, 0.f, 0.f};
#pragma unroll
    for (int ni = 0; ni < 2; ++ni) {
        const int col = wave * 32 + ni * 16 + l16;
        const float bv = b3[col];
        const float wv = Wo[col];
#pragma unroll
        for (int r = 0; r < 4; ++r)
            part[r] = fmaf(fmaxf(acc3[ni][r] + bv, 0.f), wv, part[r]);
    }
#pragma unroll
    for (int r = 0; r < 4; ++r) { QRED(part[r]) }
    if (l16 == 0) {
#pragma unroll
        for (int r = 0; r < 4; ++r)
            psum[quad * 4 + r][wave] = part[r];
    }
    __syncthreads();
    if (tid < 16)
        out[r0 + tid] = psum[tid][0] + psum[tid][1] + psum[tid][2] + psum[tid][3] + bo[0];
}

extern "C" void kernel_launch(void* const* d_in, const int* in_sizes, int n_in,
                              void* d_out, int out_size, void* d_ws, size_t ws_size,
                              hipStream_t stream) {
    const int*   fidx  = (const int*)d_in[0];
    const int*   hitem = (const int*)d_in[1];
    const int*   hauth = (const int*)d_in[2];
    const int*   hmus  = (const int*)d_in[3];
    const float* emb   = (const float*)d_in[4];
    const float* W1 = (const float*)d_in[5];
    const float* b1 = (const float*)d_in[6];
    const float* W2 = (const float*)d_in[7];
    const float* b2 = (const float*)d_in[8];
    const float* W3 = (const float*)d_in[9];
    const float* b3 = (const float*)d_in[10];
    const float* Wo = (const float*)d_in[11];
    const float* bo = (const float*)d_in[12];
    float* out = (float*)d_out;

    // workspace carve (bf16 elements, all 16B-aligned)
    u16* x   = (u16*)d_ws;                     // 4096*704
    u16* h1  = x   + (size_t)BATCH * 704;      // 4096*512
    u16* w1t = h1  + (size_t)BATCH * 512;      // 512*704
    u16* w2t = w1t + (size_t)704 * 512;        // 256*512
    u16* w3t = w2t + (size_t)512 * 256;        // 128*256

    // 2048 warm + 5120 build_x + 512 transpose blocks
    prep_kernel<<<7680, 256, 0, stream>>>(fidx, hitem, hauth, hmus, emb,
                                          W1, W2, W3, x, w1t, w2t, w3t);

    gemm_mfma<64><<<dim3(512 / 64, BATCH / 64), 256, 0, stream>>>(
        x, w1t, b1, h1, BATCH, 512, 704);

    tail_mlp<<<BATCH / 16, 256, 0, stream>>>(h1, w2t, w3t, b2, b3, Wo, bo, out);
}

// Round 6
// 461.067 us; speedup vs baseline: 1.0926x; 1.0926x over previous
//
#include <hip/hip_runtime.h>
#include <cstddef>

#define BATCH   4096
#define PAD_IDX 1000000
#define NEG_INF_F (-1e9f)

typedef __attribute__((ext_vector_type(8))) short bf16x8;   // 8 bf16 = 4 VGPRs
typedef __attribute__((ext_vector_type(4))) float f32x4;
typedef unsigned short u16;

__device__ __forceinline__ u16 f2bf(float f) {              // RNE fp32 -> bf16
    unsigned u = __float_as_uint(f);
    return (u16)((u + 0x7fffu + ((u >> 16) & 1u)) >> 16);
}

// Online-softmax update on named state (mm, dd, aa)
#define UPD(mm, dd, aa, s, v)                          \
    {                                                  \
        float nm = fmaxf(mm, (s));                     \
        float sc = __expf(mm - nm);                    \
        float e  = __expf((s) - nm);                   \
        dd = fmaf(dd, sc, e);                          \
        aa.x = fmaf(aa.x, sc, e * (v).x);              \
        aa.y = fmaf(aa.y, sc, e * (v).y);              \
        aa.z = fmaf(aa.z, sc, e * (v).z);              \
        aa.w = fmaf(aa.w, sc, e * (v).w);              \
        mm = nm;                                       \
    }

// Flash-merge state (m,d,acc) with partner at lane^P
#define MERGE(P)                                                  \
    {                                                             \
        float mo  = __shfl_xor(m, P);                             \
        float d_o = __shfl_xor(d, P);                             \
        float ax = __shfl_xor(acc.x, P);                          \
        float ay = __shfl_xor(acc.y, P);                          \
        float az = __shfl_xor(acc.z, P);                          \
        float aw = __shfl_xor(acc.w, P);                          \
        float nm = fmaxf(m, mo);                                  \
        float sA = __expf(m - nm), sB = __expf(mo - nm);          \
        d = d * sA + d_o * sB;                                    \
        acc.x = acc.x * sA + ax * sB;                             \
        acc.y = acc.y * sA + ay * sB;                             \
        acc.z = acc.z * sA + az * sB;                             \
        acc.w = acc.w * sA + aw * sB;                             \
        m = nm;                                                   \
    }

#define QRED(s)                       \
    s += __shfl_xor(s, 1);            \
    s += __shfl_xor(s, 2);            \
    s += __shfl_xor(s, 4);            \
    s += __shfl_xor(s, 8);

#define DOT4(v, a) ((v).x * (a).x + (v).y * (a).y + (v).z * (a).z + (v).w * (a).w)

// ---------------- prep: attention pools + ad gather + weight transpose (NO warm — R5 showed it regresses) ----------------
// Blocks [0, 5120):     build_x — 4 waves/block, wave split into 4x16-lane quarters;
//                       quarter q handles item l+q, lane t16 holds k=4*t16..+4.
// Blocks [5120, 5632):  32x32 LDS-tiled transpose W[K][N] fp32 -> WT[N][K] bf16.
// x row layout (704 bf16): [pool_item(64) | pool_author(64) | pool_music(64) | ad(512)]
__global__ void __launch_bounds__(256) prep_kernel(
    const int* __restrict__ fidx,
    const int* __restrict__ hist_item,
    const int* __restrict__ hist_author,
    const int* __restrict__ hist_music,
    const float* __restrict__ emb,
    const float* __restrict__ W1, const float* __restrict__ W2, const float* __restrict__ W3,
    u16* __restrict__ x,
    u16* __restrict__ w1t, u16* __restrict__ w2t, u16* __restrict__ w3t)
{
    __shared__ float tile[32][33];
    const int blk = blockIdx.x;
    const int tid = threadIdx.x;

    if (blk < 5120) {
        const int w    = blk * 4 + (tid >> 6);
        const int lane = tid & 63;
        const int t16  = lane & 15;
        const int q    = lane >> 4;

        if (w < 3 * BATCH) {
            const int h = w >> 12;
            const int b = w & (BATCH - 1);
            int L, col, off;
            const int* hrow;
            if (h == 0)      { L = 350; col = 2; off = 0;   hrow = hist_item   + (size_t)b * 350; }
            else if (h == 1) { L = 250; col = 3; off = 64;  hrow = hist_author + (size_t)b * 250; }
            else             { L = 100; col = 6; off = 128; hrow = hist_music  + (size_t)b * 100; }

            const int ad_idx = fidx[b * 8 + col];
            const float4 ad4 = *(const float4*)(emb + (size_t)ad_idx * 64 + 4 * t16);

            float m = NEG_INF_F, d = 0.f;
            float4 acc = make_float4(0.f, 0.f, 0.f, 0.f);
            float mB = NEG_INF_F, dB = 0.f;
            float4 aB = make_float4(0.f, 0.f, 0.f, 0.f);

            int l = 0;
            if (L >= 16) {
                int n0 = hrow[q], n1 = hrow[4 + q], n2 = hrow[8 + q], n3 = hrow[12 + q];
                while (true) {
                    const int i0 = n0, i1 = n1, i2 = n2, i3 = n3;
                    const float4 v0 = *(const float4*)(emb + (size_t)i0 * 64 + 4 * t16);
                    const float4 v1 = *(const float4*)(emb + (size_t)i1 * 64 + 4 * t16);
                    const float4 v2 = *(const float4*)(emb + (size_t)i2 * 64 + 4 * t16);
                    const float4 v3 = *(const float4*)(emb + (size_t)i3 * 64 + 4 * t16);
                    l += 16;
                    const bool more = (l + 16 <= L);
                    if (more) {
                        n0 = hrow[l + q];      n1 = hrow[l + 4 + q];
                        n2 = hrow[l + 8 + q];  n3 = hrow[l + 12 + q];
                    }
                    float s0 = DOT4(v0, ad4);
                    float s1 = DOT4(v1, ad4);
                    float s2 = DOT4(v2, ad4);
                    float s3 = DOT4(v3, ad4);
                    QRED(s0) QRED(s1) QRED(s2) QRED(s3)
                    if (i0 == PAD_IDX) s0 = NEG_INF_F;
                    if (i1 == PAD_IDX) s1 = NEG_INF_F;
                    if (i2 == PAD_IDX) s2 = NEG_INF_F;
                    if (i3 == PAD_IDX) s3 = NEG_INF_F;
                    UPD(m, d, acc, s0, v0)
                    UPD(mB, dB, aB, s1, v1)
                    UPD(m, d, acc, s2, v2)
                    UPD(mB, dB, aB, s3, v3)
                    if (!more) break;
                }
            }
            for (; l < L; l += 4) {
                const int li = l + q;
                const int i0 = (li < L) ? hrow[li] : PAD_IDX;
                const float4 v0 = *(const float4*)(emb + (size_t)i0 * 64 + 4 * t16);
                float s0 = DOT4(v0, ad4);
                QRED(s0)
                if (i0 == PAD_IDX) s0 = NEG_INF_F;
                UPD(m, d, acc, s0, v0)
            }

            {   // merge B into A (local)
                float nm = fmaxf(m, mB);
                float eA = __expf(m - nm), eB = __expf(mB - nm);
                d = d * eA + dB * eB;
                acc.x = acc.x * eA + aB.x * eB;
                acc.y = acc.y * eA + aB.y * eB;
                acc.z = acc.z * eA + aB.z * eB;
                acc.w = acc.w * eA + aB.w * eB;
                m = nm;
            }
            MERGE(16)
            MERGE(32)

            if (lane < 16) {
                const float inv = 1.f / d;
                uint2 p;
                p.x = (unsigned)f2bf(acc.x * inv) | ((unsigned)f2bf(acc.y * inv) << 16);
                p.y = (unsigned)f2bf(acc.z * inv) | ((unsigned)f2bf(acc.w * inv) << 16);
                *(uint2*)(x + (size_t)b * 704 + off + 4 * t16) = p;
            }
        } else {
            const int tt = w - 3 * BATCH;          // [0, 2B)
            const int b  = tt >> 1;
            const int f  = ((tt & 1) << 2) + q;
            const int idx = fidx[b * 8 + f];
            const float4 v = *(const float4*)(emb + (size_t)idx * 64 + 4 * t16);
            uint2 p;
            p.x = (unsigned)f2bf(v.x) | ((unsigned)f2bf(v.y) << 16);
            p.y = (unsigned)f2bf(v.z) | ((unsigned)f2bf(v.w) << 16);
            *(uint2*)(x + (size_t)b * 704 + 192 + (size_t)f * 64 + 4 * t16) = p;
        }
        return;
    }

    // ---- weight transpose: 32x32 fp32 tile, coalesced both ways ----
    int t = blk - 5120;
    const float* W; u16* WT; int K, N, tk, tn;
    if (t < 352)      { W = W1; WT = w1t; K = 704; N = 512; tk = t % 22; tn = t / 22; }
    else if (t < 480) { t -= 352; W = W2; WT = w2t; K = 512; N = 256; tk = t % 16; tn = t / 16; }
    else              { t -= 480; W = W3; WT = w3t; K = 256; N = 128; tk = t % 8;  tn = t / 8;  }
    const int k0 = tk * 32, n0 = tn * 32;
    const int tx = tid & 31, ty = tid >> 5;   // ty 0..7
#pragma unroll
    for (int j = 0; j < 4; ++j)
        tile[ty + 8 * j][tx] = W[(size_t)(k0 + ty + 8 * j) * N + n0 + tx];
    __syncthreads();
#pragma unroll
    for (int j = 0; j < 4; ++j)
        WT[(size_t)(n0 + ty + 8 * j) * K + k0 + tx] = f2bf(tile[tx][ty + 8 * j]);
}

// ---------------- fused MLP: out = relu(relu(relu(x@W1+b1)@W2+b2)@W3+b3) @ Wo + bo ----------------
// 256 blocks x 16 rows; h1, h2 live in LDS (bf16 — rounding points identical to the 3-kernel version).
// Layer1: wave w -> cols w*128..+128 (8 frags), K=704, W1T streamed per k-step (Bs 512x40).
// Layer2: wave w -> cols w*64..+64 (4 frags), K=512 from h1s. Layer3: wave w -> cols w*32..+32, K=256 from h2s.
// Fragments: A[m=lane&15][k=quad*8+j]; B[k=quad*8+j][n=lane&15]; C/D row=quad*4+reg, col=lane&15.
__global__ void __launch_bounds__(256) fused_mlp(
    const u16* __restrict__ x,
    const u16* __restrict__ W1T, const u16* __restrict__ W2T, const u16* __restrict__ W3T,
    const float* __restrict__ b1, const float* __restrict__ b2, const float* __restrict__ b3,
    const float* __restrict__ Wo, const float* __restrict__ bo,
    float* __restrict__ out)
{
    __shared__ u16 As16[16][40];     // A chunk 16 rows x 32 k
    __shared__ u16 Bs[512][40];      // weight chunk (reused by all layers), 40 KB
    __shared__ u16 h1s[16][520];     // 16 x 512, row stride 520
    __shared__ u16 h2s[16][264];     // 16 x 256, row stride 264
    __shared__ float psum[16][4];

    const int tid  = threadIdx.x;
    const int wave = tid >> 6, lane = tid & 63;
    const int quad = lane >> 4, l16 = lane & 15;
    const int r0 = blockIdx.x * 16;

    // ---- layer 1: K=704, N=512 ----
    f32x4 acc1[8];
#pragma unroll
    for (int i = 0; i < 8; ++i) acc1[i] = (f32x4){0.f, 0.f, 0.f, 0.f};

    for (int k0 = 0; k0 < 704; k0 += 32) {
        if (tid < 64)
            *(float4*)&As16[tid >> 2][(tid & 3) * 8] =
                *(const float4*)(x + (size_t)(r0 + (tid >> 2)) * 704 + k0 + (tid & 3) * 8);
#pragma unroll
        for (int rr = 0; rr < 512; rr += 256) {
            const u16* src = W1T + (size_t)(rr + tid) * 704 + k0;
#pragma unroll
            for (int c = 0; c < 4; ++c)
                *(float4*)&Bs[rr + tid][c * 8] = *(const float4*)(src + c * 8);
        }
        __syncthreads();

        const bf16x8 af = *(const bf16x8*)&As16[l16][quad * 8];
#pragma unroll
        for (int ni = 0; ni < 8; ++ni) {
            const bf16x8 bf = *(const bf16x8*)&Bs[wave * 128 + ni * 16 + l16][quad * 8];
            acc1[ni] = __builtin_amdgcn_mfma_f32_16x16x32_bf16(af, bf, acc1[ni], 0, 0, 0);
        }
        __syncthreads();
    }
#pragma unroll
    for (int ni = 0; ni < 8; ++ni) {
        const int col = wave * 128 + ni * 16 + l16;
        const float bv = b1[col];
#pragma unroll
        for (int r = 0; r < 4; ++r)
            h1s[quad * 4 + r][col] = f2bf(fmaxf(acc1[ni][r] + bv, 0.f));
    }
    __syncthreads();

    // ---- layer 2: K=512, N=256 ----
    f32x4 acc2[4];
#pragma unroll
    for (int i = 0; i < 4; ++i) acc2[i] = (f32x4){0.f, 0.f, 0.f, 0.f};

    for (int k0 = 0; k0 < 512; k0 += 32) {
        {
            const u16* src = W2T + (size_t)tid * 512 + k0;
#pragma unroll
            for (int c = 0; c < 4; ++c)
                *(float4*)&Bs[tid][c * 8] = *(const float4*)(src + c * 8);
        }
        __syncthreads();

        const bf16x8 af = *(const bf16x8*)&h1s[l16][k0 + quad * 8];
#pragma unroll
        for (int ni = 0; ni < 4; ++ni) {
            const bf16x8 bf = *(const bf16x8*)&Bs[wave * 64 + ni * 16 + l16][quad * 8];
            acc2[ni] = __builtin_amdgcn_mfma_f32_16x16x32_bf16(af, bf, acc2[ni], 0, 0, 0);
        }
        __syncthreads();
    }
#pragma unroll
    for (int ni = 0; ni < 4; ++ni) {
        const int col = wave * 64 + ni * 16 + l16;
        const float bv = b2[col];
#pragma unroll
        for (int r = 0; r < 4; ++r)
            h2s[quad * 4 + r][col] = f2bf(fmaxf(acc2[ni][r] + bv, 0.f));
    }
    __syncthreads();

    // ---- layer 3: K=256, N=128 ----
    f32x4 acc3[2];
#pragma unroll
    for (int i = 0; i < 2; ++i) acc3[i] = (f32x4){0.f, 0.f, 0.f, 0.f};

    for (int k0 = 0; k0 < 256; k0 += 32) {
        if (tid < 128) {
            const u16* src = W3T + (size_t)tid * 256 + k0;
#pragma unroll
            for (int c = 0; c < 4; ++c)
                *(float4*)&Bs[tid][c * 8] = *(const float4*)(src + c * 8);
        }
        __syncthreads();

        const bf16x8 af = *(const bf16x8*)&h2s[l16][k0 + quad * 8];
#pragma unroll
        for (int ni = 0; ni < 2; ++ni) {
            const bf16x8 bf = *(const bf16x8*)&Bs[wave * 32 + ni * 16 + l16][quad * 8];
            acc3[ni] = __builtin_amdgcn_mfma_f32_16x16x32_bf16(af, bf, acc3[ni], 0, 0, 0);
        }
        __syncthreads();
    }

    // epilogue: relu(+b3), dot with Wo over this wave's 32 cols, reduce over l16
    float part[4] = {0.f, 0.f, 0.f, 0.f};
#pragma unroll
    for (int ni = 0; ni < 2; ++ni) {
        const int col = wave * 32 + ni * 16 + l16;
        const float bv = b3[col];
        const float wv = Wo[col];
#pragma unroll
        for (int r = 0; r < 4; ++r)
            part[r] = fmaf(fmaxf(acc3[ni][r] + bv, 0.f), wv, part[r]);
    }
#pragma unroll
    for (int r = 0; r < 4; ++r) { QRED(part[r]) }
    if (l16 == 0) {
#pragma unroll
        for (int r = 0; r < 4; ++r)
            psum[quad * 4 + r][wave] = part[r];
    }
    __syncthreads();
    if (tid < 16)
        out[r0 + tid] = psum[tid][0] + psum[tid][1] + psum[tid][2] + psum[tid][3] + bo[0];
}

extern "C" void kernel_launch(void* const* d_in, const int* in_sizes, int n_in,
                              void* d_out, int out_size, void* d_ws, size_t ws_size,
                              hipStream_t stream) {
    const int*   fidx  = (const int*)d_in[0];
    const int*   hitem = (const int*)d_in[1];
    const int*   hauth = (const int*)d_in[2];
    const int*   hmus  = (const int*)d_in[3];
    const float* emb   = (const float*)d_in[4];
    const float* W1 = (const float*)d_in[5];
    const float* b1 = (const float*)d_in[6];
    const float* W2 = (const float*)d_in[7];
    const float* b2 = (const float*)d_in[8];
    const float* W3 = (const float*)d_in[9];
    const float* b3 = (const float*)d_in[10];
    const float* Wo = (const float*)d_in[11];
    const float* bo = (const float*)d_in[12];
    float* out = (float*)d_out;

    // workspace carve (bf16 elements, all 16B-aligned)
    u16* x   = (u16*)d_ws;                     // 4096*704
    u16* w1t = x   + (size_t)BATCH * 704;      // 512*704
    u16* w2t = w1t + (size_t)704 * 512;        // 256*512
    u16* w3t = w2t + (size_t)512 * 256;        // 128*256

    // 5120 build_x blocks + 512 transpose blocks
    prep_kernel<<<5632, 256, 0, stream>>>(fidx, hitem, hauth, hmus, emb,
                                          W1, W2, W3, x, w1t, w2t, w3t);

    fused_mlp<<<BATCH / 16, 256, 0, stream>>>(x, w1t, w2t, w3t,
                                              b1, b2, b3, Wo, bo, out);
}